// Round 5
// baseline (927.791 us; speedup 1.0000x reference)
//
#include <hip/hip_runtime.h>
#include <hip/hip_bf16.h>

typedef __bf16 bf16x8 __attribute__((ext_vector_type(8)));
typedef float  f32x4  __attribute__((ext_vector_type(4)));
typedef unsigned short u16;
typedef u16 ushort8_t __attribute__((ext_vector_type(8)));

#define PI_D 3.14159265358979323846

__device__ __forceinline__ float rfl_f(float x){
  return __builtin_bit_cast(float, __builtin_amdgcn_readfirstlane(__builtin_bit_cast(int, x)));
}
__device__ __forceinline__ u16 bf16_bits(float f){
  __bf16 b = (__bf16)f;
  return __builtin_bit_cast(u16, b);
}

// ---------------- K0: DCT / IDCT matrices (32x32 each, f32) ----------------
// Dm[k][i] = 2*cos(pi*k*(2i+1)/64)          (DCT, freq-major rows)
// Mm[i][k] = cos(pi*k*(2i+1)/64) * w[k]     (IDCT, space-major rows), w0=1/64 else 1/32
__global__ void k_init(float* __restrict__ Dm, float* __restrict__ Mm){
  for (int idx = threadIdx.x; idx < 1024; idx += 256){
    int r = idx >> 5, c = idx & 31;
    Dm[idx] = (float)(2.0 * cos(PI_D * (double)r * (double)(2*c+1) / 64.0));
    Mm[idx] = (float)(cos(PI_D * (double)c * (double)(2*r+1) / 64.0) * ((c==0)?0.5:1.0) / 32.0);
  }
}

// ---------------- KW: weight [f][c][9] -> planes wT[j][f][c] ----------------
__global__ void k_wt(const float* __restrict__ w, float* __restrict__ wT){
  int f = blockIdx.x, c = threadIdx.x;
  const float* s = w + ((size_t)f*256 + c)*9;
  #pragma unroll
  for (int j = 0; j < 9; ++j)
    wT[(size_t)j*65536 + f*256 + c] = s[j];
}

// ---------------- KA: per-image 2D DCT via MFMA, x(f32) -> Xnat(bf16 [nc][kl]) ----------------
__global__ __launch_bounds__(256) void k_dct(const float* __restrict__ x,
                                             const float* __restrict__ Dm,
                                             u16* __restrict__ Xnat){
  __shared__ __bf16 Dmb[32][40];
  __shared__ float  xl[4][32*37];
  __shared__ __bf16 t1[4][32*40];
  int t = threadIdx.x;
  for (int idx = t; idx < 1024; idx += 256)
    Dmb[idx>>5][idx&31] = (__bf16)Dm[idx];
  __syncthreads();
  int wv = t >> 6, lane = t & 63, l4 = lane & 15, g = lane >> 4;
  bf16x8 dmf[2];
  dmf[0] = *(const bf16x8*)&Dmb[l4][g*8];
  dmf[1] = *(const bf16x8*)&Dmb[16+l4][g*8];
  int img = blockIdx.x*4 + wv;            // img = n*256 + c
  const float* xs = x + (size_t)img*1024;
  float* xw = xl[wv];
  #pragma unroll
  for (int jr = 0; jr < 4; ++jr){
    int e = jr*256 + lane*4;
    float4 v = *(const float4*)(xs + e);
    float* p = xw + (e>>5)*37 + (e&31);
    p[0]=v.x; p[1]=v.y; p[2]=v.z; p[3]=v.w;
  }
  __syncthreads();
  bf16x8 bf[2];
  #pragma unroll
  for (int nn = 0; nn < 2; ++nn){
    #pragma unroll
    for (int jj = 0; jj < 8; ++jj)
      bf[nn][jj] = (__bf16)xw[(g*8+jj)*37 + nn*16 + l4];
  }
  f32x4 z = {0.f,0.f,0.f,0.f};
  __bf16* tw = t1[wv];
  #pragma unroll
  for (int m = 0; m < 2; ++m){
    #pragma unroll
    for (int nn = 0; nn < 2; ++nn){
      f32x4 d = __builtin_amdgcn_mfma_f32_16x16x32_bf16(dmf[m], bf[nn], z, 0,0,0);
      #pragma unroll
      for (int r = 0; r < 4; ++r)
        tw[(m*16 + g*4 + r)*40 + nn*16 + l4] = (__bf16)d[r];
    }
  }
  __syncthreads();
  bf16x8 a2[2];
  a2[0] = *(const bf16x8*)&tw[(l4)*40 + g*8];
  a2[1] = *(const bf16x8*)&tw[(16+l4)*40 + g*8];
  u16* xo = Xnat + (size_t)img*1024;
  #pragma unroll
  for (int m2 = 0; m2 < 2; ++m2){
    #pragma unroll
    for (int nn2 = 0; nn2 < 2; ++nn2){
      f32x4 d = __builtin_amdgcn_mfma_f32_16x16x32_bf16(a2[m2], dmf[nn2], z, 0,0,0);
      #pragma unroll
      for (int r = 0; r < 4; ++r){
        int kk = m2*16 + g*4 + r, ll = nn2*16 + l4;
        xo[kk*32 + ll] = bf16_bits(d[r]);
      }
    }
  }
}

// ---------------- KT: transpose [16384 nc][1024 kl] -> [1024 kl][16384 nc] (bf16 bits) ----------------
__global__ __launch_bounds__(256) void k_tr(const u16* __restrict__ src,
                                            u16* __restrict__ dst){
  __shared__ u16 tile[64][66];
  int klb = blockIdx.x*64, ncb = blockIdx.y*64;
  int t = threadIdx.x, r0 = t >> 4, q = t & 15;
  #pragma unroll
  for (int jr = 0; jr < 4; ++jr){
    int row = r0 + jr*16;
    ushort4 v = *(const ushort4*)(src + (size_t)(ncb+row)*1024 + klb + q*4);
    tile[row][q*4+0]=v.x; tile[row][q*4+1]=v.y; tile[row][q*4+2]=v.z; tile[row][q*4+3]=v.w;
  }
  __syncthreads();
  #pragma unroll
  for (int jr = 0; jr < 4; ++jr){
    int kr = r0 + jr*16;
    ushort4 o;
    o.x = tile[q*4+0][kr]; o.y = tile[q*4+1][kr];
    o.z = tile[q*4+2][kr]; o.w = tile[q*4+3][kr];
    *(ushort4*)(dst + (size_t)(klb+kr)*16384 + ncb + q*4) = o;
  }
}

// ---------------- KC: channel mix. Per block: 4 kl x 32 n x 64 f, K-loop over c ----------------
// R[kl][n][f] = sum_c X[kl][n][c] * K[f][c](kl),  K on-the-fly from wT planes.
// 256-thread blocks (4 waves, wave wv owns kl0+wv) -> 1-wave/SIMD granularity,
// ~3 blocks/CU co-resident. No forced reg cap below natural usage (round-4 spill lesson).
__global__ __launch_bounds__(256, 3) void k_mix(const u16* __restrict__ Xt,
                                                const float* __restrict__ wT,
                                                const float* __restrict__ Dm,
                                                u16* __restrict__ R){
  __shared__ __bf16 Xl[4][32][40];
  __shared__ __bf16 Bl[4][64][40];
  int t = threadIdx.x;
  int klg = blockIdx.x;              // 0..255
  int fb  = (blockIdx.y >> 1) * 64;  // f base
  int nb  = (blockIdx.y & 1) * 32;   // n base
  int kl0 = klg * 4;
  int kf  = kl0 >> 5;                // k (row frequency), shared by the 4 kl
  int lb  = kl0 & 31;                // l base
  float dk[3];
  #pragma unroll
  for (int a = 0; a < 3; ++a) dk[a] = rfl_f(Dm[kf*32 + a]);
  float coef[4][9];
  #pragma unroll
  for (int i = 0; i < 4; ++i){
    #pragma unroll
    for (int b = 0; b < 3; ++b){
      float dlb = Dm[(lb+i)*32 + b];
      #pragma unroll
      for (int a = 0; a < 3; ++a) coef[i][a*3+b] = rfl_f(dk[a]*dlb);
    }
  }
  int lane = t & 63, wv = t >> 6;    // wv = kli
  int l4 = lane & 15, g = lane >> 4;
  int rowi = t >> 3;                 // 0..31 : n-local (X stage) / f-local base (B gen)
  int cq   = t & 7;                  // c-quad within 32-wide chunk
  f32x4 acc[2][4];
  #pragma unroll
  for (int m = 0; m < 2; ++m){
    #pragma unroll
    for (int nn = 0; nn < 4; ++nn){ f32x4 z={0.f,0.f,0.f,0.f}; acc[m][nn]=z; }
  }
  for (int cc = 0; cc < 8; ++cc){
    int cb = cc * 32;
    // stage X: Xl[j][n][c] <- Xt[kl0+j][nb+n][cb+c]
    #pragma unroll
    for (int j = 0; j < 4; ++j){
      ushort4 v = *(const ushort4*)(Xt + (size_t)(kl0 + j)*16384 + (nb + rowi)*256 + cb + cq*4);
      *(ushort4*)((u16*)&Xl[j][rowi][cq*4]) = v;
    }
    // generate B: Bl[i][f][c] = sum_j wT[j][fb+f][cb+c] * coef[i][j], two 32-f halves
    #pragma unroll
    for (int fh = 0; fh < 2; ++fh){
      int frow = fh*32 + rowi;
      const float* wb = wT + (size_t)(fb + frow)*256 + cb + cq*4;
      float s[4][4];
      #pragma unroll
      for (int i = 0; i < 4; ++i){ s[i][0]=0.f; s[i][1]=0.f; s[i][2]=0.f; s[i][3]=0.f; }
      #pragma unroll
      for (int jc = 0; jc < 3; ++jc){
        float4 w0 = *(const float4*)(wb + (size_t)(jc*3+0)*65536);
        float4 w1 = *(const float4*)(wb + (size_t)(jc*3+1)*65536);
        float4 w2 = *(const float4*)(wb + (size_t)(jc*3+2)*65536);
        #pragma unroll
        for (int i = 0; i < 4; ++i){
          float c0 = coef[i][jc*3+0], c1 = coef[i][jc*3+1], c2 = coef[i][jc*3+2];
          s[i][0] += c0*w0.x + c1*w1.x + c2*w2.x;
          s[i][1] += c0*w0.y + c1*w1.y + c2*w2.y;
          s[i][2] += c0*w0.z + c1*w1.z + c2*w2.z;
          s[i][3] += c0*w0.w + c1*w1.w + c2*w2.w;
        }
      }
      #pragma unroll
      for (int i = 0; i < 4; ++i){
        ushort4 pv;
        pv.x = bf16_bits(s[i][0]); pv.y = bf16_bits(s[i][1]);
        pv.z = bf16_bits(s[i][2]); pv.w = bf16_bits(s[i][3]);
        *(ushort4*)((u16*)&Bl[i][frow][cq*4]) = pv;
      }
    }
    __syncthreads();
    bf16x8 af[2], bfr[4];
    af[0] = *(const bf16x8*)&Xl[wv][l4][g*8];
    af[1] = *(const bf16x8*)&Xl[wv][16 + l4][g*8];
    #pragma unroll
    for (int nn = 0; nn < 4; ++nn)
      bfr[nn] = *(const bf16x8*)&Bl[wv][nn*16 + l4][g*8];
    #pragma unroll
    for (int m = 0; m < 2; ++m){
      #pragma unroll
      for (int nn = 0; nn < 4; ++nn)
        acc[m][nn] = __builtin_amdgcn_mfma_f32_16x16x32_bf16(af[m], bfr[nn], acc[m][nn], 0,0,0);
    }
    __syncthreads();
  }
  // epilogue: R[kl][n][f] bf16 — f contiguous, 4x32B segments per store instr
  int kl = kl0 + wv;
  #pragma unroll
  for (int m = 0; m < 2; ++m){
    #pragma unroll
    for (int nn = 0; nn < 4; ++nn){
      #pragma unroll
      for (int r = 0; r < 4; ++r){
        int n = nb + m*16 + g*4 + r;
        R[((size_t)kl*64 + n)*256 + fb + nn*16 + l4] = bf16_bits(acc[m][nn][r]);
      }
    }
  }
}

// ---------------- KT-R: R [1024 kl][16384 nf] -> R2 [16384 nf][1024 kl] ----------------
__global__ __launch_bounds__(256) void k_trR(const u16* __restrict__ src,
                                             u16* __restrict__ dst){
  __shared__ u16 tile[64][66];
  int klb = blockIdx.x*64, nfb = blockIdx.y*64;
  int t = threadIdx.x, r0 = t >> 4, q = t & 15;
  #pragma unroll
  for (int jr = 0; jr < 4; ++jr){
    int row = r0 + jr*16;
    ushort4 v = *(const ushort4*)(src + (size_t)(klb+row)*16384 + nfb + q*4);
    tile[row][q*4+0]=v.x; tile[row][q*4+1]=v.y; tile[row][q*4+2]=v.z; tile[row][q*4+3]=v.w;
  }
  __syncthreads();
  #pragma unroll
  for (int jr = 0; jr < 4; ++jr){
    int kr = r0 + jr*16;
    ushort4 o;
    o.x = tile[q*4+0][kr]; o.y = tile[q*4+1][kr];
    o.z = tile[q*4+2][kr]; o.w = tile[q*4+3][kr];
    *(ushort4*)(dst + (size_t)(nfb+kr)*1024 + klb + q*4) = o;
  }
}

// ---------------- KD: per-image 2D IDCT via MFMA + crop, R2(bf16 [nf][kl]) -> out ----------------
__global__ __launch_bounds__(256) void k_idct(const u16* __restrict__ R2,
                                              const float* __restrict__ Mm,
                                              float* __restrict__ out){
  __shared__ __bf16 Mmb[32][40];
  __shared__ u16   rl[4][32][42];   // 42-pad: conflict-free fragment gathers
  __shared__ __bf16 t2[4][32*40];
  int t = threadIdx.x;
  for (int idx = t; idx < 1024; idx += 256)
    Mmb[idx>>5][idx&31] = (__bf16)Mm[idx];
  __syncthreads();
  int wv = t>>6, lane = t&63, l4 = lane&15, g = lane>>4;
  bf16x8 mmf[2];
  mmf[0] = *(const bf16x8*)&Mmb[l4][g*8];
  mmf[1] = *(const bf16x8*)&Mmb[16+l4][g*8];
  int img = blockIdx.x*4 + wv;            // img = n*256 + f
  const u16* rs = R2 + (size_t)img*1024;
  #pragma unroll
  for (int jr = 0; jr < 2; ++jr){
    int e = jr*512 + lane*8;
    ushort8_t v = *(const ushort8_t*)(rs + e);
    unsigned int* p32 = (unsigned int*)&rl[wv][e>>5][e&31];
    #pragma unroll
    for (int i = 0; i < 4; ++i)
      p32[i] = (unsigned int)v[2*i] | ((unsigned int)v[2*i+1] << 16);
  }
  __syncthreads();
  // phase1: T2[h][l] = sum_k MH[h,k] * R[k,l]
  bf16x8 bfr[2];
  #pragma unroll
  for (int nn = 0; nn < 2; ++nn){
    #pragma unroll
    for (int jj = 0; jj < 8; ++jj)
      bfr[nn][jj] = __builtin_bit_cast(__bf16, rl[wv][g*8+jj][nn*16 + l4]);
  }
  f32x4 z = {0.f,0.f,0.f,0.f};
  __bf16* tw = t2[wv];
  #pragma unroll
  for (int m = 0; m < 2; ++m){
    #pragma unroll
    for (int nn = 0; nn < 2; ++nn){
      f32x4 d = __builtin_amdgcn_mfma_f32_16x16x32_bf16(mmf[m], bfr[nn], z, 0,0,0);
      #pragma unroll
      for (int r = 0; r < 4; ++r)
        tw[(m*16 + g*4 + r)*40 + nn*16 + l4] = (__bf16)d[r];
    }
  }
  __syncthreads();
  // phase2: out[h][w] = sum_l T2[h][l] * MW[w][l], crop 30x30
  bf16x8 a2[2];
  a2[0] = *(const bf16x8*)&tw[l4*40 + g*8];
  a2[1] = *(const bf16x8*)&tw[(16+l4)*40 + g*8];
  float* oo = out + (size_t)img*900;
  #pragma unroll
  for (int m2 = 0; m2 < 2; ++m2){
    #pragma unroll
    for (int nn2 = 0; nn2 < 2; ++nn2){
      f32x4 d = __builtin_amdgcn_mfma_f32_16x16x32_bf16(a2[m2], mmf[nn2], z, 0,0,0);
      #pragma unroll
      for (int r = 0; r < 4; ++r){
        int h = m2*16 + g*4 + r, w2 = nn2*16 + l4;
        if (h < 30 && w2 < 30) oo[h*30 + w2] = d[r];
      }
    }
  }
}

// ---------------- launch ----------------
// ws layout (bytes) — peak 103,030,784 (== round-1 proven size):
//   Dm   @ 0          (4 KB)
//   Mm   @ 4096       (4 KB)
//   wT   @ 8192       (2,359,296)
//   Xt   @ 2367488    (33,554,432)   [kl][n][c] bf16
//   Xnat @ 35921920   (33,554,432)   [nc][kl] bf16 (dead after k_tr)
//   R2   @ 35921920   (33,554,432)   [nf][kl] bf16 (overlays Xnat)
//   R    @ 69476352   (33,554,432)   [kl][n][f] bf16
extern "C" void kernel_launch(void* const* d_in, const int* in_sizes, int n_in,
                              void* d_out, int out_size, void* d_ws, size_t ws_size,
                              hipStream_t stream){
  (void)in_sizes; (void)n_in; (void)out_size; (void)ws_size;
  const float* x  = (const float*)d_in[0];
  const float* w  = (const float*)d_in[1];
  float* out = (float*)d_out;
  char* ws = (char*)d_ws;
  float* Dm = (float*)(ws + 0);
  float* Mm = (float*)(ws + 4096);
  float* wT = (float*)(ws + 8192);
  u16* Xt   = (u16*)(ws + 2367488);
  u16* Xnat = (u16*)(ws + 35921920);
  u16* R2   = (u16*)(ws + 35921920);
  u16* R    = (u16*)(ws + 69476352);

  hipLaunchKernelGGL(k_init, dim3(1),         dim3(256), 0, stream, Dm, Mm);
  hipLaunchKernelGGL(k_wt,   dim3(256),       dim3(256), 0, stream, w, wT);
  hipLaunchKernelGGL(k_dct,  dim3(4096),      dim3(256), 0, stream, x, Dm, Xnat);
  hipLaunchKernelGGL(k_tr,   dim3(16,256),    dim3(256), 0, stream, Xnat, Xt);
  hipLaunchKernelGGL(k_mix,  dim3(256,8),     dim3(256), 0, stream, Xt, wT, Dm, R);
  hipLaunchKernelGGL(k_trR,  dim3(16,256),    dim3(256), 0, stream, R, R2);
  hipLaunchKernelGGL(k_idct, dim3(4096),      dim3(256), 0, stream, R2, Mm, out);
}

// Round 6
// 113.924 us; speedup vs baseline: 8.1440x; 8.1440x over previous
//
#include <hip/hip_runtime.h>
#include <hip/hip_bf16.h>

typedef __bf16 bf16x8 __attribute__((ext_vector_type(8)));
typedef float  f32x4  __attribute__((ext_vector_type(4)));
typedef unsigned short u16;
typedef u16 ushort8_t __attribute__((ext_vector_type(8)));

#define PI_D 3.14159265358979323846

__device__ __forceinline__ float rfl_f(float x){
  return __builtin_bit_cast(float, __builtin_amdgcn_readfirstlane(__builtin_bit_cast(int, x)));
}
__device__ __forceinline__ u16 bf16_bits(float f){
  __bf16 b = (__bf16)f;
  return __builtin_bit_cast(u16, b);
}

// ---------------- K0: DCT / IDCT matrices (32x32 each, f32) ----------------
// Dm[k][i] = 2*cos(pi*k*(2i+1)/64)          (DCT, freq-major rows)
// Mm[i][k] = cos(pi*k*(2i+1)/64) * w[k]     (IDCT, space-major rows), w0=1/64 else 1/32
__global__ void k_init(float* __restrict__ Dm, float* __restrict__ Mm){
  for (int idx = threadIdx.x; idx < 1024; idx += 256){
    int r = idx >> 5, c = idx & 31;
    Dm[idx] = (float)(2.0 * cos(PI_D * (double)r * (double)(2*c+1) / 64.0));
    Mm[idx] = (float)(cos(PI_D * (double)c * (double)(2*r+1) / 64.0) * ((c==0)?0.5:1.0) / 32.0);
  }
}

// ---------------- KW: weight [f][c][9] -> planes wT[j][f][c] ----------------
__global__ void k_wt(const float* __restrict__ w, float* __restrict__ wT){
  int f = blockIdx.x, c = threadIdx.x;
  const float* s = w + ((size_t)f*256 + c)*9;
  #pragma unroll
  for (int j = 0; j < 9; ++j)
    wT[(size_t)j*65536 + f*256 + c] = s[j];
}

// ---------------- KA: per-image 2D DCT via MFMA, x(f32) -> Xnat(bf16 [nc][kl]) ----------------
__global__ __launch_bounds__(256) void k_dct(const float* __restrict__ x,
                                             const float* __restrict__ Dm,
                                             u16* __restrict__ Xnat){
  __shared__ __bf16 Dmb[32][40];
  __shared__ float  xl[4][32*37];
  __shared__ __bf16 t1[4][32*40];
  int t = threadIdx.x;
  for (int idx = t; idx < 1024; idx += 256)
    Dmb[idx>>5][idx&31] = (__bf16)Dm[idx];
  __syncthreads();
  int wv = t >> 6, lane = t & 63, l4 = lane & 15, g = lane >> 4;
  bf16x8 dmf[2];
  dmf[0] = *(const bf16x8*)&Dmb[l4][g*8];
  dmf[1] = *(const bf16x8*)&Dmb[16+l4][g*8];
  int img = blockIdx.x*4 + wv;            // img = n*256 + c
  const float* xs = x + (size_t)img*1024;
  float* xw = xl[wv];
  #pragma unroll
  for (int jr = 0; jr < 4; ++jr){
    int e = jr*256 + lane*4;
    float4 v = *(const float4*)(xs + e);
    float* p = xw + (e>>5)*37 + (e&31);
    p[0]=v.x; p[1]=v.y; p[2]=v.z; p[3]=v.w;
  }
  __syncthreads();
  bf16x8 bf[2];
  #pragma unroll
  for (int nn = 0; nn < 2; ++nn){
    #pragma unroll
    for (int jj = 0; jj < 8; ++jj)
      bf[nn][jj] = (__bf16)xw[(g*8+jj)*37 + nn*16 + l4];
  }
  f32x4 z = {0.f,0.f,0.f,0.f};
  __bf16* tw = t1[wv];
  #pragma unroll
  for (int m = 0; m < 2; ++m){
    #pragma unroll
    for (int nn = 0; nn < 2; ++nn){
      f32x4 d = __builtin_amdgcn_mfma_f32_16x16x32_bf16(dmf[m], bf[nn], z, 0,0,0);
      #pragma unroll
      for (int r = 0; r < 4; ++r)
        tw[(m*16 + g*4 + r)*40 + nn*16 + l4] = (__bf16)d[r];
    }
  }
  __syncthreads();
  bf16x8 a2[2];
  a2[0] = *(const bf16x8*)&tw[(l4)*40 + g*8];
  a2[1] = *(const bf16x8*)&tw[(16+l4)*40 + g*8];
  u16* xo = Xnat + (size_t)img*1024;
  #pragma unroll
  for (int m2 = 0; m2 < 2; ++m2){
    #pragma unroll
    for (int nn2 = 0; nn2 < 2; ++nn2){
      f32x4 d = __builtin_amdgcn_mfma_f32_16x16x32_bf16(a2[m2], dmf[nn2], z, 0,0,0);
      #pragma unroll
      for (int r = 0; r < 4; ++r){
        int kk = m2*16 + g*4 + r, ll = nn2*16 + l4;
        xo[kk*32 + ll] = bf16_bits(d[r]);
      }
    }
  }
}

// ---------------- KT: transpose [16384 nc][1024 kl] -> [1024 kl][16384 nc] (bf16 bits) ----------------
__global__ __launch_bounds__(256) void k_tr(const u16* __restrict__ src,
                                            u16* __restrict__ dst){
  __shared__ u16 tile[64][66];
  int klb = blockIdx.x*64, ncb = blockIdx.y*64;
  int t = threadIdx.x, r0 = t >> 4, q = t & 15;
  #pragma unroll
  for (int jr = 0; jr < 4; ++jr){
    int row = r0 + jr*16;
    ushort4 v = *(const ushort4*)(src + (size_t)(ncb+row)*1024 + klb + q*4);
    tile[row][q*4+0]=v.x; tile[row][q*4+1]=v.y; tile[row][q*4+2]=v.z; tile[row][q*4+3]=v.w;
  }
  __syncthreads();
  #pragma unroll
  for (int jr = 0; jr < 4; ++jr){
    int kr = r0 + jr*16;
    ushort4 o;
    o.x = tile[q*4+0][kr]; o.y = tile[q*4+1][kr];
    o.z = tile[q*4+2][kr]; o.w = tile[q*4+3][kr];
    *(ushort4*)(dst + (size_t)(klb+kr)*16384 + ncb + q*4) = o;
  }
}

// ---------------- KC: channel mix. Per block: 4 kl x 64 n x 64 f, K-loop over c ----------------
// R[kl][n][f] = sum_c X[kl][n][c] * K[f][c](kl),  K on-the-fly from wT planes.
// Direct-A global->reg (Xt row-major == A-frag layout; proven r4).
// B double-buffered in LDS -> ONE barrier per cc (proven r4).
// Factorized gen (84 FMA/thread) + rolling wq prefetch.
// NO min-waves launch bound (r4/r5 lesson: forced caps => scratch spill).
__global__ __launch_bounds__(512) void k_mix(const u16* __restrict__ Xt,
                                             const float* __restrict__ wT,
                                             const float* __restrict__ Dm,
                                             u16* __restrict__ R){
  __shared__ __bf16 Bl[2][4][64][40];
  int t = threadIdx.x;
  int klg = blockIdx.x;          // 0..255
  int fb  = blockIdx.y * 64;     // f base
  int kl0 = klg * 4;
  int kf  = kl0 >> 5;            // k (row frequency), shared by the 4 kl
  int lb  = kl0 & 31;            // l base
  float dk[3], dl[4][3];
  #pragma unroll
  for (int a = 0; a < 3; ++a) dk[a] = rfl_f(Dm[kf*32 + a]);
  #pragma unroll
  for (int i = 0; i < 4; ++i){
    #pragma unroll
    for (int b = 0; b < 3; ++b) dl[i][b] = rfl_f(Dm[(lb+i)*32 + b]);
  }
  int lane = t & 63, wv = t >> 6;
  int kli = wv & 3, nh = wv >> 2;
  int l4 = lane & 15, g = lane >> 4;
  int rowi = t >> 3;             // 0..63 : f-local row for B-gen
  int cq   = t & 7;              // c-quad within 32-wide chunk
  f32x4 acc[2][4];
  #pragma unroll
  for (int m = 0; m < 2; ++m){
    #pragma unroll
    for (int nn = 0; nn < 4; ++nn){ f32x4 z={0.f,0.f,0.f,0.f}; acc[m][nn]=z; }
  }
  // per-lane global A-frag base: Xt[kl0+kli][nh*32 + l4][g*8]  (+16*256 for m=1)
  const u16* xb = Xt + (size_t)(kl0 + kli)*16384 + (size_t)(nh*32 + l4)*256 + g*8;
  const float* wb = wT + (size_t)(fb + rowi)*256 + cq*4;
  // prologue: wq[j] = wT[j][fb+rowi][cq*4 .. +3] for cc=0
  float4 wq[9];
  #pragma unroll
  for (int j = 0; j < 9; ++j) wq[j] = *(const float4*)(wb + (size_t)j*65536);
  for (int cc = 0; cc < 8; ++cc){
    int p = cc & 1;
    // A-frags for THIS cc: latency hidden behind gen + barrier
    bf16x8 afc[2];
    afc[0] = *(const bf16x8*)(xb + cc*32);
    afc[1] = *(const bf16x8*)(xb + cc*32 + 16*256);
    // gen (factorized): tmp[b][e] = sum_a dk[a]*w[a*3+b][e]; rolling reload per b-group
    const float* wn = wb + (cc + 1)*32;
    float tmp[3][4];
    #pragma unroll
    for (int b = 0; b < 3; ++b){
      float4 w0 = wq[b], w1 = wq[3+b], w2 = wq[6+b];
      tmp[b][0] = dk[0]*w0.x + dk[1]*w1.x + dk[2]*w2.x;
      tmp[b][1] = dk[0]*w0.y + dk[1]*w1.y + dk[2]*w2.y;
      tmp[b][2] = dk[0]*w0.z + dk[1]*w1.z + dk[2]*w2.z;
      tmp[b][3] = dk[0]*w0.w + dk[1]*w1.w + dk[2]*w2.w;
      if (cc < 7){
        wq[b]   = *(const float4*)(wn + (size_t)(b  )*65536);
        wq[3+b] = *(const float4*)(wn + (size_t)(3+b)*65536);
        wq[6+b] = *(const float4*)(wn + (size_t)(6+b)*65536);
      }
    }
    #pragma unroll
    for (int i = 0; i < 4; ++i){
      float s0 = dl[i][0]*tmp[0][0] + dl[i][1]*tmp[1][0] + dl[i][2]*tmp[2][0];
      float s1 = dl[i][0]*tmp[0][1] + dl[i][1]*tmp[1][1] + dl[i][2]*tmp[2][1];
      float s2 = dl[i][0]*tmp[0][2] + dl[i][1]*tmp[1][2] + dl[i][2]*tmp[2][2];
      float s3 = dl[i][0]*tmp[0][3] + dl[i][1]*tmp[1][3] + dl[i][2]*tmp[2][3];
      ushort4 pv;
      pv.x = bf16_bits(s0); pv.y = bf16_bits(s1);
      pv.z = bf16_bits(s2); pv.w = bf16_bits(s3);
      *(ushort4*)((u16*)&Bl[p][i][rowi][cq*4]) = pv;
    }
    __syncthreads();
    bf16x8 bfr[4];
    #pragma unroll
    for (int nn = 0; nn < 4; ++nn)
      bfr[nn] = *(const bf16x8*)&Bl[p][kli][nn*16 + l4][g*8];
    #pragma unroll
    for (int m = 0; m < 2; ++m){
      #pragma unroll
      for (int nn = 0; nn < 4; ++nn)
        acc[m][nn] = __builtin_amdgcn_mfma_f32_16x16x32_bf16(afc[m], bfr[nn], acc[m][nn], 0,0,0);
    }
  }
  // epilogue: R[kl][n][f] bf16 — f contiguous, 4x32B segments per store instr
  int kl = kl0 + kli;
  #pragma unroll
  for (int m = 0; m < 2; ++m){
    #pragma unroll
    for (int nn = 0; nn < 4; ++nn){
      #pragma unroll
      for (int r = 0; r < 4; ++r){
        int n = nh*32 + m*16 + g*4 + r;
        R[((size_t)kl*64 + n)*256 + fb + nn*16 + l4] = bf16_bits(acc[m][nn][r]);
      }
    }
  }
}

// ---------------- KT-R: R [1024 kl][16384 nf] -> R2 [16384 nf][1024 kl] ----------------
__global__ __launch_bounds__(256) void k_trR(const u16* __restrict__ src,
                                             u16* __restrict__ dst){
  __shared__ u16 tile[64][66];
  int klb = blockIdx.x*64, nfb = blockIdx.y*64;
  int t = threadIdx.x, r0 = t >> 4, q = t & 15;
  #pragma unroll
  for (int jr = 0; jr < 4; ++jr){
    int row = r0 + jr*16;
    ushort4 v = *(const ushort4*)(src + (size_t)(klb+row)*16384 + nfb + q*4);
    tile[row][q*4+0]=v.x; tile[row][q*4+1]=v.y; tile[row][q*4+2]=v.z; tile[row][q*4+3]=v.w;
  }
  __syncthreads();
  #pragma unroll
  for (int jr = 0; jr < 4; ++jr){
    int kr = r0 + jr*16;
    ushort4 o;
    o.x = tile[q*4+0][kr]; o.y = tile[q*4+1][kr];
    o.z = tile[q*4+2][kr]; o.w = tile[q*4+3][kr];
    *(ushort4*)(dst + (size_t)(nfb+kr)*1024 + klb + q*4) = o;
  }
}

// ---------------- KD: per-image 2D IDCT via MFMA + crop, R2(bf16 [nf][kl]) -> out ----------------
__global__ __launch_bounds__(256) void k_idct(const u16* __restrict__ R2,
                                              const float* __restrict__ Mm,
                                              float* __restrict__ out){
  __shared__ __bf16 Mmb[32][40];
  __shared__ u16   rl[4][32][42];   // 42-pad: conflict-free fragment gathers
  __shared__ __bf16 t2[4][32*40];
  int t = threadIdx.x;
  for (int idx = t; idx < 1024; idx += 256)
    Mmb[idx>>5][idx&31] = (__bf16)Mm[idx];
  __syncthreads();
  int wv = t>>6, lane = t&63, l4 = lane&15, g = lane>>4;
  bf16x8 mmf[2];
  mmf[0] = *(const bf16x8*)&Mmb[l4][g*8];
  mmf[1] = *(const bf16x8*)&Mmb[16+l4][g*8];
  int img = blockIdx.x*4 + wv;            // img = n*256 + f
  const u16* rs = R2 + (size_t)img*1024;
  #pragma unroll
  for (int jr = 0; jr < 2; ++jr){
    int e = jr*512 + lane*8;
    ushort8_t v = *(const ushort8_t*)(rs + e);
    unsigned int* p32 = (unsigned int*)&rl[wv][e>>5][e&31];
    #pragma unroll
    for (int i = 0; i < 4; ++i)
      p32[i] = (unsigned int)v[2*i] | ((unsigned int)v[2*i+1] << 16);
  }
  __syncthreads();
  // phase1: T2[h][l] = sum_k MH[h,k] * R[k,l]
  bf16x8 bfr[2];
  #pragma unroll
  for (int nn = 0; nn < 2; ++nn){
    #pragma unroll
    for (int jj = 0; jj < 8; ++jj)
      bfr[nn][jj] = __builtin_bit_cast(__bf16, rl[wv][g*8+jj][nn*16 + l4]);
  }
  f32x4 z = {0.f,0.f,0.f,0.f};
  __bf16* tw = t2[wv];
  #pragma unroll
  for (int m = 0; m < 2; ++m){
    #pragma unroll
    for (int nn = 0; nn < 2; ++nn){
      f32x4 d = __builtin_amdgcn_mfma_f32_16x16x32_bf16(mmf[m], bfr[nn], z, 0,0,0);
      #pragma unroll
      for (int r = 0; r < 4; ++r)
        tw[(m*16 + g*4 + r)*40 + nn*16 + l4] = (__bf16)d[r];
    }
  }
  __syncthreads();
  // phase2: out[h][w] = sum_l T2[h][l] * MW[w][l], crop 30x30
  bf16x8 a2[2];
  a2[0] = *(const bf16x8*)&tw[l4*40 + g*8];
  a2[1] = *(const bf16x8*)&tw[(16+l4)*40 + g*8];
  float* oo = out + (size_t)img*900;
  #pragma unroll
  for (int m2 = 0; m2 < 2; ++m2){
    #pragma unroll
    for (int nn2 = 0; nn2 < 2; ++nn2){
      f32x4 d = __builtin_amdgcn_mfma_f32_16x16x32_bf16(a2[m2], mmf[nn2], z, 0,0,0);
      #pragma unroll
      for (int r = 0; r < 4; ++r){
        int h = m2*16 + g*4 + r, w2 = nn2*16 + l4;
        if (h < 30 && w2 < 30) oo[h*30 + w2] = d[r];
      }
    }
  }
}

// ---------------- launch ----------------
// ws layout (bytes) — peak 103,030,784 (== round-1 proven size):
//   Dm   @ 0          (4 KB)
//   Mm   @ 4096       (4 KB)
//   wT   @ 8192       (2,359,296)
//   Xt   @ 2367488    (33,554,432)   [kl][n][c] bf16
//   Xnat @ 35921920   (33,554,432)   [nc][kl] bf16 (dead after k_tr)
//   R2   @ 35921920   (33,554,432)   [nf][kl] bf16 (overlays Xnat)
//   R    @ 69476352   (33,554,432)   [kl][n][f] bf16
extern "C" void kernel_launch(void* const* d_in, const int* in_sizes, int n_in,
                              void* d_out, int out_size, void* d_ws, size_t ws_size,
                              hipStream_t stream){
  (void)in_sizes; (void)n_in; (void)out_size; (void)ws_size;
  const float* x  = (const float*)d_in[0];
  const float* w  = (const float*)d_in[1];
  float* out = (float*)d_out;
  char* ws = (char*)d_ws;
  float* Dm = (float*)(ws + 0);
  float* Mm = (float*)(ws + 4096);
  float* wT = (float*)(ws + 8192);
  u16* Xt   = (u16*)(ws + 2367488);
  u16* Xnat = (u16*)(ws + 35921920);
  u16* R2   = (u16*)(ws + 35921920);
  u16* R    = (u16*)(ws + 69476352);

  hipLaunchKernelGGL(k_init, dim3(1),         dim3(256), 0, stream, Dm, Mm);
  hipLaunchKernelGGL(k_wt,   dim3(256),       dim3(256), 0, stream, w, wT);
  hipLaunchKernelGGL(k_dct,  dim3(4096),      dim3(256), 0, stream, x, Dm, Xnat);
  hipLaunchKernelGGL(k_tr,   dim3(16,256),    dim3(256), 0, stream, Xnat, Xt);
  hipLaunchKernelGGL(k_mix,  dim3(256,4),     dim3(512), 0, stream, Xt, wT, Dm, R);
  hipLaunchKernelGGL(k_trR,  dim3(16,256),    dim3(256), 0, stream, R, R2);
  hipLaunchKernelGGL(k_idct, dim3(4096),      dim3(256), 0, stream, R2, Mm, out);
}